// Round 1
// baseline (505.446 us; speedup 1.0000x reference)
//
#include <hip/hip_runtime.h>

#define NUM_CLASSES 8

__global__ __launch_bounds__(256) void confusion_matrix_kernel(
    const float* __restrict__ y_true,
    const float* __restrict__ y_pred,
    float* __restrict__ out,
    int n)
{
    __shared__ unsigned int hist[NUM_CLASSES * NUM_CLASSES];
    for (int i = threadIdx.x; i < NUM_CLASSES * NUM_CLASSES; i += blockDim.x)
        hist[i] = 0u;
    __syncthreads();

    const size_t stride = (size_t)gridDim.x * blockDim.x;
    for (size_t idx = (size_t)blockIdx.x * blockDim.x + threadIdx.x; idx < (size_t)n; idx += stride) {
        const float4* t4 = (const float4*)(y_true + idx * NUM_CLASSES);
        const float4* p4 = (const float4*)(y_pred + idx * NUM_CLASSES);
        float4 ta = t4[0];
        float4 tb = t4[1];
        float4 pa = p4[0];
        float4 pb = p4[1];

        float tv[8] = {ta.x, ta.y, ta.z, ta.w, tb.x, tb.y, tb.z, tb.w};
        float pv[8] = {pa.x, pa.y, pa.z, pa.w, pb.x, pb.y, pb.z, pb.w};

        int ti = 0; float tm = tv[0];
        #pragma unroll
        for (int j = 1; j < 8; ++j) {
            if (tv[j] > tm) { tm = tv[j]; ti = j; }   // strict > => first index wins ties
        }
        int pi = 0; float pm = pv[0];
        #pragma unroll
        for (int j = 1; j < 8; ++j) {
            if (pv[j] > pm) { pm = pv[j]; pi = j; }
        }

        atomicAdd(&hist[ti * NUM_CLASSES + pi], 1u);
    }
    __syncthreads();

    for (int i = threadIdx.x; i < NUM_CLASSES * NUM_CLASSES; i += blockDim.x) {
        unsigned int v = hist[i];
        if (v) atomicAdd(&out[i], (float)v);
    }
}

extern "C" void kernel_launch(void* const* d_in, const int* in_sizes, int n_in,
                              void* d_out, int out_size, void* d_ws, size_t ws_size,
                              hipStream_t stream)
{
    const float* y_true = (const float*)d_in[0];
    const float* y_pred = (const float*)d_in[1];
    float* out = (float*)d_out;

    const int n = in_sizes[0] / NUM_CLASSES;  // 8388608 rows

    // Harness re-poisons d_out with 0xAA before every timed replay: zero it.
    hipMemsetAsync(out, 0, (size_t)out_size * sizeof(float), stream);

    const int block = 256;
    const int grid = 2048;  // grid-stride: ~16 rows/thread, saturates 256 CUs
    confusion_matrix_kernel<<<grid, block, 0, stream>>>(y_true, y_pred, out, n);
}